// Round 3
// baseline (208.731 us; speedup 1.0000x reference)
//
#include <hip/hip_runtime.h>

#define LEAKY_SLOPE 0.2f

constexpr int B_   = 16;
constexpr int N_   = 4096;
constexpr int K_   = 4096;
constexpr int IN_  = 16384;   // K + 3K
constexpr int H1_  = 1024;
constexpr int H2_  = 512;
constexpr int OUT_ = 256;

// encode tiling: 32 n-chunks x 128 points (2KB LDS), 8 k per thread
constexpr int NCH = 32;
constexpr int NPC = N_ / NCH;   // 128
constexpr int KPT = 8;
constexpr int KTB = 256 * KPT;  // 2048 k per block -> grid.x = 2

// -------------------------------------------------------------------------
// Partial argmin over an n-chunk, folded via u64 atomicMin on
// (orderable_e2_bits << 32 | n).  e2 = pn - 2*cross (bn constant in the
// argmin over n; validated rounds 3-5).  6 VALU ops per (k,n) pair; one
// ds_read_b128 feeds 8 k's.  grid = (2,16,32) = 1024 blocks, 16 waves/CU.
// -------------------------------------------------------------------------
__global__ __launch_bounds__(256) void enc_partial(
    const float* __restrict__ pc, const float* __restrict__ basis,
    unsigned long long* __restrict__ packed)
{
#pragma clang fp contract(off)
    __shared__ float4 pts[NPC];
    const int kt = blockIdx.x;
    const int b  = blockIdx.y;
    const int c  = blockIdx.z;
    const int n0 = c * NPC;

    if (threadIdx.x < NPC) {
        const float* pp = pc + ((size_t)b * N_ + n0 + threadIdx.x) * 3;
        float x = pp[0], y = pp[1], z = pp[2];
        pts[threadIdx.x] = make_float4(x, y, z, (x * x + y * y) + z * z);
    }
    __syncthreads();

    const int k0 = kt * KTB + (int)threadIdx.x;
    float nbx[KPT], nby[KPT], nbz[KPT], best[KPT];
    int   bi[KPT];
#pragma unroll
    for (int q = 0; q < KPT; ++q) {
        int k = k0 + q * 256;
        nbx[q] = -2.0f * basis[k * 3 + 0];
        nby[q] = -2.0f * basis[k * 3 + 1];
        nbz[q] = -2.0f * basis[k * 3 + 2];
        best[q] = 3.4028235e38f;
        bi[q] = 0;
    }

#pragma unroll 2
    for (int n = 0; n < NPC; ++n) {
        float4 p = pts[n];
#pragma unroll
        for (int q = 0; q < KPT; ++q) {
            float e2 = __builtin_fmaf(nbx[q], p.x,
                        __builtin_fmaf(nby[q], p.y,
                         __builtin_fmaf(nbz[q], p.z, p.w)));
            if (e2 < best[q]) { best[q] = e2; bi[q] = n0 + n; }  // strict <
        }
    }

#pragma unroll
    for (int q = 0; q < KPT; ++q) {
        unsigned u = __float_as_uint(best[q]);
        u = (u & 0x80000000u) ? ~u : (u | 0x80000000u);   // monotone map
        unsigned long long v = ((unsigned long long)u << 32) | (unsigned)bi[q];
        atomicMin(&packed[(size_t)b * K_ + (k0 + q * 256)], v);
    }
}

// -------------------------------------------------------------------------
// Unpack argmin index, gather nearest point, write bps feature row.
// -------------------------------------------------------------------------
__global__ __launch_bounds__(256) void enc_finish(
    const float* __restrict__ pc, const float* __restrict__ basis,
    const unsigned long long* __restrict__ packed,
    float* __restrict__ bps_out)
{
#pragma clang fp contract(off)
    const int t = blockIdx.x * 256 + (int)threadIdx.x;   // 0 .. B*K-1
    const int b = t >> 12;
    const int k = t & (K_ - 1);

    const int bi = (int)(unsigned)(packed[t] & 0xffffffffull);

    const float* p = pc + ((size_t)b * N_ + bi) * 3;
    float dx = p[0] - basis[k * 3 + 0];
    float dy = p[1] - basis[k * 3 + 1];
    float dz = p[2] - basis[k * 3 + 2];
    float dist = sqrtf((dx * dx + dy * dy) + dz * dz);

    float* row = bps_out + (size_t)b * IN_;
    row[k]              = dist;
    row[K_ + 3 * k + 0] = dx;
    row[K_ + 3 * k + 1] = dy;
    row[K_ + 3 * k + 2] = dz;
}

// -------------------------------------------------------------------------
// L1 GEMM v2: read-W-once structure.
//   grid (8 colblocks x 64 chunks) = 512 blocks, 4 waves/block (2 blk/CU).
//   Wave w owns i-slice [i0 + w*64, +64) of the 256-i chunk; lane -> 2 cols
//   (float2 W load, 512B/wave).  Each wave carries ALL 16 batch accumulators
//   -> 32 FMA per 8B W load (old: 8 FMA per 8B + 4 SMEM); W1 is loaded
//   exactly once chip-wide (old: 4x per block via 4 lockstep waves).
//   A values = 16 wave-uniform scalar loads (bps rows, scalar-cache hot).
//   LDS [4][64][33] (pad 33 -> conflict-free) folds the 4 k-slices; store
//   one partial per block -> partial layout [chunk][16][H1] unchanged.
// -------------------------------------------------------------------------
template<int ILEN, int NCOLS>
__global__ __launch_bounds__(256) void gemm1(
    const float* __restrict__ A, const float* __restrict__ W,
    float* __restrict__ part)
{
    __shared__ float red[4][64][33];
    const int lane = (int)threadIdx.x & 63;
    const int w    = __builtin_amdgcn_readfirstlane((int)threadIdx.x >> 6);
    const int j0   = blockIdx.x * 128 + lane * 2;
    const int i0   = blockIdx.y * ILEN + w * (ILEN / 4);

    float2 acc[16];
#pragma unroll
    for (int r = 0; r < 16; ++r) acc[r] = make_float2(0.f, 0.f);

#pragma unroll 4
    for (int i = i0; i < i0 + ILEN / 4; ++i) {
        float2 wv = *(const float2*)(W + (size_t)i * NCOLS + j0);
#pragma unroll
        for (int r = 0; r < 16; ++r) {
            float a = A[(size_t)r * IN_ + i];       // wave-uniform -> s_load
            acc[r].x = __builtin_fmaf(a, wv.x, acc[r].x);
            acc[r].y = __builtin_fmaf(a, wv.y, acc[r].y);
        }
    }

#pragma unroll
    for (int r = 0; r < 16; ++r) {
        red[w][lane][2 * r]     = acc[r].x;
        red[w][lane][2 * r + 1] = acc[r].y;
    }
    __syncthreads();

    // cross-wave fold: thread (w, lane) -> batches [4w, 4w+4) x col pair lane
    float* base = part + (size_t)blockIdx.y * 16 * NCOLS + blockIdx.x * 128 + lane * 2;
    const int b0 = w * 4;
#pragma unroll
    for (int b = b0; b < b0 + 4; ++b) {
        float sx = 0.f, sy = 0.f;
#pragma unroll
        for (int ww = 0; ww < 4; ++ww) {
            sx += red[ww][lane][2 * b];
            sy += red[ww][lane][2 * b + 1];
        }
        *(float2*)(base + (size_t)b * NCOLS) = make_float2(sx, sy);
    }
}

// -------------------------------------------------------------------------
// Reduce 64 chunk-partials + bias + leaky -> h1T[col][16]
// -------------------------------------------------------------------------
__global__ __launch_bounds__(256) void reduce_act1(
    const float* __restrict__ part, const float* __restrict__ bias,
    float* __restrict__ outT)
{
    const int p = blockIdx.x * 256 + (int)threadIdx.x;   // b*H1 + col
    float s = 0.0f;
#pragma unroll 8
    for (int c = 0; c < 64; ++c) s += part[(size_t)c * (16 * H1_) + p];
    const int col = p & (H1_ - 1);
    const int b   = p >> 10;
    s += bias[col];
    s = fmaxf(s, LEAKY_SLOPE * s);
    outT[(size_t)col * 16 + b] = s;
}

// -------------------------------------------------------------------------
// Small fused GEMM (L2/L3): one dispatch, full K. 512 threads = 8 waves;
// wave w -> k-slice; lane -> one column; 16 batch accs; LDS cross-wave
// reduce; bias (+leaky) inline.  AT layout [i][16].
// -------------------------------------------------------------------------
template<int KDIM, int NCOLS>
__global__ __launch_bounds__(512) void gemm_small(
    const float* __restrict__ AT, const float* __restrict__ W,
    const float* __restrict__ bias,
    float* __restrict__ outT, float* __restrict__ out_rm)
{
    __shared__ float red[8][64][17];
    const int lane = (int)threadIdx.x & 63;
    const int w    = __builtin_amdgcn_readfirstlane((int)threadIdx.x >> 6);
    const int j    = blockIdx.x * 64 + lane;
    constexpr int KQ = KDIM / 8;
    const int i0 = w * KQ;

    float acc[16];
#pragma unroll
    for (int r = 0; r < 16; ++r) acc[r] = 0.0f;

#pragma unroll 4
    for (int i = i0; i < i0 + KQ; ++i) {
        float wv = W[(size_t)i * NCOLS + j];
        const float4* Ar = (const float4*)(AT + (size_t)i * 16);
        float4 q0 = Ar[0], q1 = Ar[1], q2 = Ar[2], q3 = Ar[3];
        acc[0]  = __builtin_fmaf(q0.x, wv, acc[0]);
        acc[1]  = __builtin_fmaf(q0.y, wv, acc[1]);
        acc[2]  = __builtin_fmaf(q0.z, wv, acc[2]);
        acc[3]  = __builtin_fmaf(q0.w, wv, acc[3]);
        acc[4]  = __builtin_fmaf(q1.x, wv, acc[4]);
        acc[5]  = __builtin_fmaf(q1.y, wv, acc[5]);
        acc[6]  = __builtin_fmaf(q1.z, wv, acc[6]);
        acc[7]  = __builtin_fmaf(q1.w, wv, acc[7]);
        acc[8]  = __builtin_fmaf(q2.x, wv, acc[8]);
        acc[9]  = __builtin_fmaf(q2.y, wv, acc[9]);
        acc[10] = __builtin_fmaf(q2.z, wv, acc[10]);
        acc[11] = __builtin_fmaf(q2.w, wv, acc[11]);
        acc[12] = __builtin_fmaf(q3.x, wv, acc[12]);
        acc[13] = __builtin_fmaf(q3.y, wv, acc[13]);
        acc[14] = __builtin_fmaf(q3.z, wv, acc[14]);
        acc[15] = __builtin_fmaf(q3.w, wv, acc[15]);
    }

#pragma unroll
    for (int r = 0; r < 16; ++r) red[w][lane][r] = acc[r];
    __syncthreads();

#pragma unroll
    for (int q = 0; q < 2; ++q) {
        int p  = (int)threadIdx.x * 2 + q;   // col_local*16 + batch
        int cl = p >> 4;
        int bt = p & 15;
        float s = bias[blockIdx.x * 64 + cl];
#pragma unroll
        for (int ww = 0; ww < 8; ++ww) s += red[ww][cl][bt];
        if (outT) {
            s = fmaxf(s, LEAKY_SLOPE * s);
            outT[((size_t)blockIdx.x * 64 + cl) * 16 + bt] = s;
        }
        if (out_rm) {
            out_rm[(size_t)bt * NCOLS + blockIdx.x * 64 + cl] = s;
        }
    }
}

// -------------------------------------------------------------------------
extern "C" void kernel_launch(void* const* d_in, const int* in_sizes, int n_in,
                              void* d_out, int out_size, void* d_ws, size_t ws_size,
                              hipStream_t stream)
{
    const float* pc    = (const float*)d_in[0];
    const float* basis = (const float*)d_in[1];
    const float* W1    = (const float*)d_in[2];
    const float* b1    = (const float*)d_in[3];
    const float* W2    = (const float*)d_in[4];
    const float* b2    = (const float*)d_in[5];
    const float* W3    = (const float*)d_in[6];
    const float* b3    = (const float*)d_in[7];

    float* out   = (float*)d_out;
    float* gfeat = out;                 // [16][256]
    float* bps   = out + B_ * OUT_;     // [16][16384]

    char* ws = (char*)d_ws;
    unsigned long long* packed = (unsigned long long*)ws;        // 512KB
    float* partial = (float*)(ws + (size_t)1024 * 1024);         // 4MB
    float* h1T     = (float*)(ws + (size_t)5 * 1024 * 1024);     // 64KB
    float* h2T     = (float*)(ws + (size_t)5 * 1024 * 1024 + 64 * 1024); // 32KB

    // 1) init packed keys to +inf
    hipMemsetAsync(packed, 0xFF, (size_t)B_ * K_ * 8, stream);
    // 2) partial argmin, atomic fold (1024 blocks, 16 waves/CU)
    enc_partial<<<dim3(K_ / KTB, B_, NCH), 256, 0, stream>>>(pc, basis, packed);
    // 3) gather + write bps feature
    enc_finish<<<(B_ * K_) / 256, 256, 0, stream>>>(pc, basis, packed, bps);
    // 4) L1 GEMM [16,16384]@[16384,1024]; read-W-once, 16-batch waves
    gemm1<256, H1_><<<dim3(8, 64), 256, 0, stream>>>(bps, W1, partial);
    // 5) reduce + bias + leaky -> h1T
    reduce_act1<<<(H1_ * 16) / 256, 256, 0, stream>>>(partial, b1, h1T);
    // 6) L2 fused [16,1024]@[1024,512]
    gemm_small<1024, H2_><<<8, 512, 0, stream>>>(h1T, W2, b2, h2T, nullptr);
    // 7) L3 fused [16,512]@[512,256] -> final output
    gemm_small<512, OUT_><<<4, 512, 0, stream>>>(h2T, W3, b3, nullptr, gfeat);
}

// Round 4
// 176.797 us; speedup vs baseline: 1.1806x; 1.1806x over previous
//
#include <hip/hip_runtime.h>

#define LEAKY_SLOPE 0.2f

constexpr int B_   = 16;
constexpr int N_   = 4096;
constexpr int K_   = 4096;
constexpr int IN_  = 16384;   // K + 3K
constexpr int H1_  = 1024;
constexpr int H2_  = 512;
constexpr int OUT_ = 256;

// encode tiling: 32 n-chunks x 128 points (2KB LDS), 8 k per thread
constexpr int NCH = 32;
constexpr int NPC = N_ / NCH;   // 128
constexpr int KPT = 8;
constexpr int KTB = 256 * KPT;  // 2048 k per block -> grid.x = 2

// -------------------------------------------------------------------------
// Partial argmin over an n-chunk.  v3: NO atomics — each block streams its
// 2048 chunk-min keys (orderable_e2_bits<<32 | n) to a private slot
// chunkmin[c][b][k]; a fused reduce+finish kernel folds the 32 chunks.
// Replaces 2.1M contended u64 atomicMin (L2 RMW serialization) with 16 MB
// coalesced streaming, and kills the 512KB memset dispatch.
// e2 = pn - 2*cross (bn constant in argmin over n; validated).  6 VALU ops
// per (k,n); one broadcast ds_read_b128 feeds 8 k's.  grid (2,16,32).
// -------------------------------------------------------------------------
__global__ __launch_bounds__(256) void enc_partial(
    const float* __restrict__ pc, const float* __restrict__ basis,
    unsigned long long* __restrict__ chunkmin)
{
#pragma clang fp contract(off)
    __shared__ float4 pts[NPC];
    const int kt = blockIdx.x;
    const int b  = blockIdx.y;
    const int c  = blockIdx.z;
    const int n0 = c * NPC;

    if (threadIdx.x < NPC) {
        const float* pp = pc + ((size_t)b * N_ + n0 + threadIdx.x) * 3;
        float x = pp[0], y = pp[1], z = pp[2];
        pts[threadIdx.x] = make_float4(x, y, z, (x * x + y * y) + z * z);
    }
    __syncthreads();

    const int k0 = kt * KTB + (int)threadIdx.x;
    float nbx[KPT], nby[KPT], nbz[KPT], best[KPT];
    int   bi[KPT];
#pragma unroll
    for (int q = 0; q < KPT; ++q) {
        int k = k0 + q * 256;
        nbx[q] = -2.0f * basis[k * 3 + 0];
        nby[q] = -2.0f * basis[k * 3 + 1];
        nbz[q] = -2.0f * basis[k * 3 + 2];
        best[q] = 3.4028235e38f;
        bi[q] = 0;
    }

#pragma unroll 2
    for (int n = 0; n < NPC; ++n) {
        float4 p = pts[n];
#pragma unroll
        for (int q = 0; q < KPT; ++q) {
            float e2 = __builtin_fmaf(nbx[q], p.x,
                        __builtin_fmaf(nby[q], p.y,
                         __builtin_fmaf(nbz[q], p.z, p.w)));
            if (e2 < best[q]) { best[q] = e2; bi[q] = n0 + n; }  // strict <
        }
    }

    unsigned long long* dst = chunkmin + ((size_t)(c * B_ + b)) * K_;
#pragma unroll
    for (int q = 0; q < KPT; ++q) {
        unsigned u = __float_as_uint(best[q]);
        u = (u & 0x80000000u) ? ~u : (u | 0x80000000u);   // monotone map
        dst[k0 + q * 256] =
            ((unsigned long long)u << 32) | (unsigned)bi[q];
    }
}

// -------------------------------------------------------------------------
// Fold 32 chunk-mins per (b,k) (bit-identical to the old atomicMin result),
// unpack index, gather nearest point, write bps feature row.
// 256 blocks x 256 thr; 16 MB coalesced read.
// -------------------------------------------------------------------------
__global__ __launch_bounds__(256) void enc_reduce_finish(
    const float* __restrict__ pc, const float* __restrict__ basis,
    const unsigned long long* __restrict__ chunkmin,
    float* __restrict__ bps_out)
{
#pragma clang fp contract(off)
    const int t = blockIdx.x * 256 + (int)threadIdx.x;   // 0 .. B*K-1
    const int b = t >> 12;
    const int k = t & (K_ - 1);

    unsigned long long vmin = 0xFFFFFFFFFFFFFFFFull;
#pragma unroll 8
    for (int c = 0; c < NCH; ++c) {
        unsigned long long v = chunkmin[((size_t)(c * B_ + b)) * K_ + k];
        vmin = (v < vmin) ? v : vmin;
    }
    const int bi = (int)(unsigned)(vmin & 0xffffffffull);

    const float* p = pc + ((size_t)b * N_ + bi) * 3;
    float dx = p[0] - basis[k * 3 + 0];
    float dy = p[1] - basis[k * 3 + 1];
    float dz = p[2] - basis[k * 3 + 2];
    float dist = sqrtf((dx * dx + dy * dy) + dz * dz);

    float* row = bps_out + (size_t)b * IN_;
    row[k]              = dist;
    row[K_ + 3 * k + 0] = dx;
    row[K_ + 3 * k + 1] = dy;
    row[K_ + 3 * k + 2] = dz;
}

// -------------------------------------------------------------------------
// L1 GEMM (unchanged from round 0, harness-validated): read-W-once.
// grid (8 colblocks x 64 chunks); wave w -> i-slice; lane -> 2 cols;
// all 16 batch accumulators per wave (32 FMA per 8B W load).
// -------------------------------------------------------------------------
template<int ILEN, int NCOLS>
__global__ __launch_bounds__(256) void gemm1(
    const float* __restrict__ A, const float* __restrict__ W,
    float* __restrict__ part)
{
    __shared__ float red[4][64][33];
    const int lane = (int)threadIdx.x & 63;
    const int w    = __builtin_amdgcn_readfirstlane((int)threadIdx.x >> 6);
    const int j0   = blockIdx.x * 128 + lane * 2;
    const int i0   = blockIdx.y * ILEN + w * (ILEN / 4);

    float2 acc[16];
#pragma unroll
    for (int r = 0; r < 16; ++r) acc[r] = make_float2(0.f, 0.f);

#pragma unroll 4
    for (int i = i0; i < i0 + ILEN / 4; ++i) {
        float2 wv = *(const float2*)(W + (size_t)i * NCOLS + j0);
#pragma unroll
        for (int r = 0; r < 16; ++r) {
            float a = A[(size_t)r * IN_ + i];       // wave-uniform -> s_load
            acc[r].x = __builtin_fmaf(a, wv.x, acc[r].x);
            acc[r].y = __builtin_fmaf(a, wv.y, acc[r].y);
        }
    }

#pragma unroll
    for (int r = 0; r < 16; ++r) {
        red[w][lane][2 * r]     = acc[r].x;
        red[w][lane][2 * r + 1] = acc[r].y;
    }
    __syncthreads();

    float* base = part + (size_t)blockIdx.y * 16 * NCOLS + blockIdx.x * 128 + lane * 2;
    const int b0 = w * 4;
#pragma unroll
    for (int b = b0; b < b0 + 4; ++b) {
        float sx = 0.f, sy = 0.f;
#pragma unroll
        for (int ww = 0; ww < 4; ++ww) {
            sx += red[ww][lane][2 * b];
            sy += red[ww][lane][2 * b + 1];
        }
        *(float2*)(base + (size_t)b * NCOLS) = make_float2(sx, sy);
    }
}

// -------------------------------------------------------------------------
// Reduce 64 chunk-partials + bias + leaky -> h1T[col][16]  (unchanged)
// -------------------------------------------------------------------------
__global__ __launch_bounds__(256) void reduce_act1(
    const float* __restrict__ part, const float* __restrict__ bias,
    float* __restrict__ outT)
{
    const int p = blockIdx.x * 256 + (int)threadIdx.x;   // b*H1 + col
    float s = 0.0f;
#pragma unroll 8
    for (int c = 0; c < 64; ++c) s += part[(size_t)c * (16 * H1_) + p];
    const int col = p & (H1_ - 1);
    const int b   = p >> 10;
    s += bias[col];
    s = fmaxf(s, LEAKY_SLOPE * s);
    outT[(size_t)col * 16 + b] = s;
}

// -------------------------------------------------------------------------
// L2 GEMM, split-K: grid (8 colblocks x 8 kslices) = 64 blocks (vs 8).
// Wave w of slice s -> 32 i's; lane -> 1 col; 16 batch accs; LDS fold.
// No bias/act here — folded into gemm_last's A-prep.
// part layout: [slice][col][16]
// -------------------------------------------------------------------------
template<int KDIM, int NCOLS>
__global__ __launch_bounds__(256) void gemm_mid(
    const float* __restrict__ AT, const float* __restrict__ W,
    float* __restrict__ part)
{
    __shared__ float red[4][64][17];
    const int lane = (int)threadIdx.x & 63;
    const int w    = __builtin_amdgcn_readfirstlane((int)threadIdx.x >> 6);
    const int cb   = blockIdx.x;
    const int s    = blockIdx.y;
    const int j    = cb * 64 + lane;
    constexpr int KS = KDIM / 8;    // 128 i per slice
    constexpr int KW = KS / 4;      // 32 i per wave
    const int i0 = s * KS + w * KW;

    float acc[16];
#pragma unroll
    for (int r = 0; r < 16; ++r) acc[r] = 0.0f;

#pragma unroll 4
    for (int i = i0; i < i0 + KW; ++i) {
        float wv = W[(size_t)i * NCOLS + j];
        const float4* Ar = (const float4*)(AT + (size_t)i * 16);
        float4 q0 = Ar[0], q1 = Ar[1], q2 = Ar[2], q3 = Ar[3];
        acc[0]  = __builtin_fmaf(q0.x, wv, acc[0]);
        acc[1]  = __builtin_fmaf(q0.y, wv, acc[1]);
        acc[2]  = __builtin_fmaf(q0.z, wv, acc[2]);
        acc[3]  = __builtin_fmaf(q0.w, wv, acc[3]);
        acc[4]  = __builtin_fmaf(q1.x, wv, acc[4]);
        acc[5]  = __builtin_fmaf(q1.y, wv, acc[5]);
        acc[6]  = __builtin_fmaf(q1.z, wv, acc[6]);
        acc[7]  = __builtin_fmaf(q1.w, wv, acc[7]);
        acc[8]  = __builtin_fmaf(q2.x, wv, acc[8]);
        acc[9]  = __builtin_fmaf(q2.y, wv, acc[9]);
        acc[10] = __builtin_fmaf(q2.z, wv, acc[10]);
        acc[11] = __builtin_fmaf(q2.w, wv, acc[11]);
        acc[12] = __builtin_fmaf(q3.x, wv, acc[12]);
        acc[13] = __builtin_fmaf(q3.y, wv, acc[13]);
        acc[14] = __builtin_fmaf(q3.z, wv, acc[14]);
        acc[15] = __builtin_fmaf(q3.w, wv, acc[15]);
    }

#pragma unroll
    for (int r = 0; r < 16; ++r) red[w][lane][r] = acc[r];
    __syncthreads();

#pragma unroll
    for (int q = 0; q < 4; ++q) {
        int p  = (int)threadIdx.x * 4 + q;   // 1024 vals: col_local*16 + batch
        int cl = p >> 4;
        int bt = p & 15;
        float ssum = 0.0f;
#pragma unroll
        for (int ww = 0; ww < 4; ++ww) ssum += red[ww][cl][bt];
        part[((size_t)s * NCOLS + cb * 64 + cl) * 16 + bt] = ssum;
    }
}

// -------------------------------------------------------------------------
// L3 GEMM, split-K, with layer-2 epilogue folded into A-prep:
// grid (4 colblocks x 8 kslices) = 32 blocks.  Each block reduces the 8
// h2 k-slices for its 64 i's (+b2, leaky) into an LDS A-tile, then does
// the usual lane-per-col / 16-batch-acc MMA against W3.
// part layout: [slice][col][16]
// -------------------------------------------------------------------------
template<int KDIM, int NCOLS>
__global__ __launch_bounds__(256) void gemm_last(
    const float* __restrict__ h2part, const float* __restrict__ b2,
    const float* __restrict__ W, float* __restrict__ part)
{
    __shared__ float aT[64][20];        // [i_local][batch], pad 20 (16B-aligned rows)
    __shared__ float red[4][64][17];
    const int lane = (int)threadIdx.x & 63;
    const int w    = __builtin_amdgcn_readfirstlane((int)threadIdx.x >> 6);
    const int cb   = blockIdx.x;
    const int s    = blockIdx.y;
    constexpr int KS = KDIM / 8;        // 64 i per slice

    // A-prep: thread -> (i_local = tid>>2, batch quad = (tid&3)*4)
    {
        const int il  = (int)threadIdx.x >> 2;
        const int btq = ((int)threadIdx.x & 3) * 4;
        const int i   = s * KS + il;
        float4 sum = make_float4(0.f, 0.f, 0.f, 0.f);
#pragma unroll
        for (int sl = 0; sl < 8; ++sl) {
            const float4 v = *(const float4*)(h2part +
                ((size_t)sl * H2_ + i) * 16 + btq);
            sum.x += v.x; sum.y += v.y; sum.z += v.z; sum.w += v.w;
        }
        const float bb = b2[i];
        sum.x += bb; sum.y += bb; sum.z += bb; sum.w += bb;
        sum.x = fmaxf(sum.x, LEAKY_SLOPE * sum.x);
        sum.y = fmaxf(sum.y, LEAKY_SLOPE * sum.y);
        sum.z = fmaxf(sum.z, LEAKY_SLOPE * sum.z);
        sum.w = fmaxf(sum.w, LEAKY_SLOPE * sum.w);
        *(float4*)&aT[il][btq] = sum;
    }
    __syncthreads();

    const int j  = cb * 64 + lane;
    const int i0 = w * 16;              // 16 i per wave
    float acc[16];
#pragma unroll
    for (int r = 0; r < 16; ++r) acc[r] = 0.0f;

#pragma unroll 4
    for (int il = i0; il < i0 + 16; ++il) {
        float wv = W[((size_t)(s * KS + il)) * NCOLS + j];
        float4 q0 = *(const float4*)&aT[il][0];
        float4 q1 = *(const float4*)&aT[il][4];
        float4 q2 = *(const float4*)&aT[il][8];
        float4 q3 = *(const float4*)&aT[il][12];
        acc[0]  = __builtin_fmaf(q0.x, wv, acc[0]);
        acc[1]  = __builtin_fmaf(q0.y, wv, acc[1]);
        acc[2]  = __builtin_fmaf(q0.z, wv, acc[2]);
        acc[3]  = __builtin_fmaf(q0.w, wv, acc[3]);
        acc[4]  = __builtin_fmaf(q1.x, wv, acc[4]);
        acc[5]  = __builtin_fmaf(q1.y, wv, acc[5]);
        acc[6]  = __builtin_fmaf(q1.z, wv, acc[6]);
        acc[7]  = __builtin_fmaf(q1.w, wv, acc[7]);
        acc[8]  = __builtin_fmaf(q2.x, wv, acc[8]);
        acc[9]  = __builtin_fmaf(q2.y, wv, acc[9]);
        acc[10] = __builtin_fmaf(q2.z, wv, acc[10]);
        acc[11] = __builtin_fmaf(q2.w, wv, acc[11]);
        acc[12] = __builtin_fmaf(q3.x, wv, acc[12]);
        acc[13] = __builtin_fmaf(q3.y, wv, acc[13]);
        acc[14] = __builtin_fmaf(q3.z, wv, acc[14]);
        acc[15] = __builtin_fmaf(q3.w, wv, acc[15]);
    }

#pragma unroll
    for (int r = 0; r < 16; ++r) red[w][lane][r] = acc[r];
    __syncthreads();

#pragma unroll
    for (int q = 0; q < 4; ++q) {
        int p  = (int)threadIdx.x * 4 + q;
        int cl = p >> 4;
        int bt = p & 15;
        float ssum = 0.0f;
#pragma unroll
        for (int ww = 0; ww < 4; ++ww) ssum += red[ww][cl][bt];
        part[((size_t)s * NCOLS + cb * 64 + cl) * 16 + bt] = ssum;
    }
}

// -------------------------------------------------------------------------
// Final: fold 8 h3 k-slices + b3 -> gfeat [16][256]
// -------------------------------------------------------------------------
__global__ __launch_bounds__(256) void out_final(
    const float* __restrict__ h3part, const float* __restrict__ b3,
    float* __restrict__ out)
{
    const int t   = blockIdx.x * 256 + (int)threadIdx.x;  // 0..4095
    const int col = t >> 4;
    const int bt  = t & 15;
    float s = b3[col];
#pragma unroll
    for (int sl = 0; sl < 8; ++sl)
        s += h3part[((size_t)sl * OUT_ + col) * 16 + bt];
    out[(size_t)bt * OUT_ + col] = s;
}

// -------------------------------------------------------------------------
extern "C" void kernel_launch(void* const* d_in, const int* in_sizes, int n_in,
                              void* d_out, int out_size, void* d_ws, size_t ws_size,
                              hipStream_t stream)
{
    const float* pc    = (const float*)d_in[0];
    const float* basis = (const float*)d_in[1];
    const float* W1    = (const float*)d_in[2];
    const float* b1    = (const float*)d_in[3];
    const float* W2    = (const float*)d_in[4];
    const float* b2    = (const float*)d_in[5];
    const float* W3    = (const float*)d_in[6];
    const float* b3    = (const float*)d_in[7];

    float* out   = (float*)d_out;
    float* gfeat = out;                 // [16][256]
    float* bps   = out + B_ * OUT_;     // [16][16384]

    char* ws = (char*)d_ws;
    unsigned long long* chunkmin = (unsigned long long*)ws;          // 16 MB
    float* partial = (float*)(ws + (size_t)16 * 1024 * 1024);        // 4 MB
    float* h1T     = (float*)(ws + (size_t)20 * 1024 * 1024);        // 64 KB
    float* h2part  = (float*)(ws + (size_t)20 * 1024 * 1024 + 64 * 1024);   // 256 KB
    float* h3part  = (float*)(ws + (size_t)20 * 1024 * 1024 + 320 * 1024);  // 128 KB

    // 1) partial argmin per chunk -> private slots (no memset, no atomics)
    enc_partial<<<dim3(K_ / KTB, B_, NCH), 256, 0, stream>>>(pc, basis, chunkmin);
    // 2) fold 32 chunks + gather + write bps feature
    enc_reduce_finish<<<(B_ * K_) / 256, 256, 0, stream>>>(pc, basis, chunkmin, bps);
    // 3) L1 GEMM [16,16384]@[16384,1024]; read-W-once, 16-batch waves
    gemm1<256, H1_><<<dim3(8, 64), 256, 0, stream>>>(bps, W1, partial);
    // 4) reduce + bias + leaky -> h1T
    reduce_act1<<<(H1_ * 16) / 256, 256, 0, stream>>>(partial, b1, h1T);
    // 5) L2 split-K GEMM [16,1024]@[1024,512] -> h2part[8][512][16]
    gemm_mid<1024, H2_><<<dim3(8, 8), 256, 0, stream>>>(h1T, W2, h2part);
    // 6) L3 split-K GEMM (layer-2 reduce+act folded into A-prep) -> h3part
    gemm_last<512, OUT_><<<dim3(4, 8), 256, 0, stream>>>(h2part, b2, W3, h3part);
    // 7) fold slices + b3 -> final output
    out_final<<<16, 256, 0, stream>>>(h3part, b3, gfeat);
}